// Round 2
// baseline (177.172 us; speedup 1.0000x reference)
//
#include <hip/hip_runtime.h>

#define T_DIM 512
#define B_DIM 8192
#define GB 16      // batch columns per block
#define NC 64      // time chunks
#define LC 8       // timesteps per chunk  (NC*LC == T_DIM)
#define GAMMA 0.99f

// Phase A: read inputs once, build per-t affine-scan coefficients in
// GUARANTEED registers (macro-expanded scalars r0..r7/p0..p7/w0..w7 — the
// array form was never SROA'd and lived in scratch: WRITE_SIZE showed
// 16-32 floats/thread of spill across rounds 0-1).
// Scan: 16 threads serially compose NC=64 chunk composites per column.
// Phase B: replay chunk from scalars with corrected carry; accumulate
// critic (= adv^2) and min(surr1, surr2); block-reduce to partials.
//
// XCD swizzle: logical blocks 2k,2k+1 share 128B cache lines (64B of
// columns each). Default dispatch puts them on different XCDs -> duplicate
// L2 fills. Swizzle gives each XCD 64 consecutive logical blocks.
__launch_bounds__(1024, 8)
__global__ void vtrace_main(const float* __restrict__ prob,
                            const float* __restrict__ aprob,
                            const float* __restrict__ v,
                            const float* __restrict__ nv,
                            const float* __restrict__ rw,
                            const int* __restrict__ act,
                            const int* __restrict__ dnn,
                            float* __restrict__ partials) {
    __shared__ float Sc[NC][GB];
    __shared__ float Mc[NC][GB];
    __shared__ float Cin[NC][GB];
    __shared__ float red[32];

    const int tid = threadIdx.x;
    const int bl  = tid & (GB - 1);
    const int c   = tid >> 4;
    // XCD-aware swizzle: 512 blocks, 8 XCDs, 64 consecutive logical
    // blocks per XCD (bijective since 512 % 8 == 0).
    const int swz = (blockIdx.x & 7) * (512 / 8) + (blockIdx.x >> 3);
    const int b   = swz * GB + bl;
    const int t0  = c * LC;

    float S = 0.0f, M = 1.0f;
    float r0,r1,r2,r3,r4,r5,r6,r7;
    float p0,p1,p2,p3,p4,p5,p6,p7;
    float w0,w1,w2,w3,w4,w5,w6,w7;

    const float2* __restrict__ prob2  = (const float2*)prob;
    const float2* __restrict__ aprob2 = (const float2*)aprob;
    const size_t base = (size_t)t0 * B_DIM + b;

#define STEPA(i)                                                            \
    {                                                                       \
        const size_t idx = base + (size_t)(i) * B_DIM;                      \
        float2 pr = prob2[idx];                                             \
        float2 qr = aprob2[idx];                                            \
        float vvi = v[idx];                                                 \
        float rr  = rw[idx];                                                \
        int   a   = act[idx];                                               \
        int   d   = dnn[idx];                                               \
        float pa    = a ? pr.y : pr.x;                                      \
        float qa    = a ? qr.y : qr.x;                                      \
        float ratio = (pa * (qr.x + qr.y)) / ((pr.x + pr.y) * qa);          \
        float rho   = fminf(ratio, 1.0f);                                   \
        float m     = d ? 0.0f : GAMMA * rho;                               \
        float p     = rho * (rr - vvi);                                     \
        r##i = __uint_as_float(__float_as_uint(ratio) |                     \
                               ((unsigned)d << 31));                        \
        p##i = p;                                                           \
        w##i = vvi;                                                         \
        S = (vvi + p) + m * S;                                              \
        M = m * M;                                                          \
    }

    STEPA(7) STEPA(6) STEPA(5) STEPA(4) STEPA(3) STEPA(2) STEPA(1) STEPA(0)
#undef STEPA

    Sc[c][bl] = S;
    Mc[c][bl] = M;
    __syncthreads();

    // serial cross-chunk scan (reverse over time), one thread per column
    if (tid < GB) {
        float carry = nv[(size_t)(T_DIM - 1) * B_DIM + swz * GB + tid];
#pragma unroll 8
        for (int cc = NC - 1; cc >= 0; --cc) {
            Cin[cc][tid] = carry;                  // carry entering chunk cc
            carry = fmaf(Mc[cc][tid], carry, Sc[cc][tid]);
        }
    }
    __syncthreads();

    float carry  = Cin[c][bl];
    float critic = 0.0f, msum = 0.0f;

#define STEPB(i)                                                            \
    {                                                                       \
        const unsigned u  = __float_as_uint(r##i);                          \
        const float r_    = __uint_as_float(u & 0x7fffffffu);               \
        const float m     = ((int)u < 0) ? 0.0f : GAMMA * fminf(r_, 1.0f);  \
        const float adv   = fmaf(m, carry, p##i);                           \
        carry = w##i + adv;                                                 \
        critic = fmaf(adv, adv, critic);                                    \
        msum += (adv >= 0.0f) ? fminf(r_, 1.2f) * adv                       \
                              : fmaxf(r_, 0.8f) * adv;                      \
    }

    STEPB(7) STEPB(6) STEPB(5) STEPB(4) STEPB(3) STEPB(2) STEPB(1) STEPB(0)
#undef STEPB

    // block reduction: wave64 shuffle then cross-wave via LDS (16 waves)
#pragma unroll
    for (int off = 32; off > 0; off >>= 1) {
        critic += __shfl_down(critic, off, 64);
        msum   += __shfl_down(msum, off, 64);
    }
    const int wave = tid >> 6;
    if ((tid & 63) == 0) { red[wave] = critic; red[16 + wave] = msum; }
    __syncthreads();
    if (tid == 0) {
        float cs = 0.0f, ms = 0.0f;
#pragma unroll
        for (int w = 0; w < 16; ++w) { cs += red[w]; ms += red[16 + w]; }
        partials[swz]       = cs;   // critic partial (SoA for finalize)
        partials[512 + swz] = ms;   // min-surrogate partial
    }
}

__global__ void vtrace_final(const float* __restrict__ partials,
                             float* __restrict__ out) {
    __shared__ float red[16];
    const int tid = threadIdx.x;  // 512 threads, one per main-block partial
    float cs = partials[tid];
    float ms = partials[512 + tid];
#pragma unroll
    for (int off = 32; off > 0; off >>= 1) {
        cs += __shfl_down(cs, off, 64);
        ms += __shfl_down(ms, off, 64);
    }
    const int wave = tid >> 6;
    if ((tid & 63) == 0) { red[wave] = cs; red[8 + wave] = ms; }
    __syncthreads();
    if (tid == 0) {
        float c = 0.0f, m = 0.0f;
#pragma unroll
        for (int w = 0; w < 8; ++w) { c += red[w]; m += red[8 + w]; }
        const float invN = 1.0f / (float)((size_t)T_DIM * B_DIM); // exact pow2
        // total = actor + critic = -mean(min(surr)) + 0.5*mean(adv^2)
        out[0] = 0.5f * c * invN - m * invN;
    }
}

extern "C" void kernel_launch(void* const* d_in, const int* in_sizes, int n_in,
                              void* d_out, int out_size, void* d_ws, size_t ws_size,
                              hipStream_t stream) {
    const float* prob  = (const float*)d_in[0];
    const float* aprob = (const float*)d_in[1];
    const float* v     = (const float*)d_in[2];
    const float* nv    = (const float*)d_in[3];
    const float* rw    = (const float*)d_in[4];
    const int*   act   = (const int*)d_in[5];
    const int*   dnn   = (const int*)d_in[6];
    float* partials = (float*)d_ws;   // 1024 floats used
    float* out      = (float*)d_out;

    vtrace_main<<<B_DIM / GB, GB * NC, 0, stream>>>(prob, aprob, v, nv, rw,
                                                    act, dnn, partials);
    vtrace_final<<<1, 512, 0, stream>>>(partials, out);
}

// Round 3
// 169.409 us; speedup vs baseline: 1.0458x; 1.0458x over previous
//
#include <hip/hip_runtime.h>

#define T_DIM 512
#define B_DIM 8192
#define GB 16      // batch columns per block
#define NC 64      // time chunks
#define LC 8       // timesteps per chunk  (NC*LC == T_DIM)
#define GAMMA 0.99f

// Phase A: issue ALL chunk loads first (48 load instrs into named scalars,
// ~64 VGPRs in flight) -> maximal memory-level parallelism; then compute
// per-t affine-scan coefficients into guaranteed registers.
// __launch_bounds__(1024,4) gives the allocator a 128-VGPR budget so the
// load cluster fits WITHOUT scratch spill (round 1-2 evidence: at the
// 64-VGPR cap the allocator serialized loads; WRITE_SIZE 5KB proved the
// macro-scalar form itself no longer spills).
// Scan: 16 threads serially compose NC=64 chunk composites per column.
// Phase B: replay chunk from scalars with corrected carry; accumulate
// critic (= adv^2) and min(surr1, surr2); block-reduce to partials.
__launch_bounds__(1024, 4)
__global__ void vtrace_main(const float* __restrict__ prob,
                            const float* __restrict__ aprob,
                            const float* __restrict__ v,
                            const float* __restrict__ nv,
                            const float* __restrict__ rw,
                            const int* __restrict__ act,
                            const int* __restrict__ dnn,
                            float* __restrict__ partials) {
    __shared__ float Sc[NC][GB];
    __shared__ float Mc[NC][GB];
    __shared__ float Cin[NC][GB];
    __shared__ float red[32];

    const int tid = threadIdx.x;
    const int bl  = tid & (GB - 1);
    const int c   = tid >> 4;
    const int b   = blockIdx.x * GB + bl;   // swizzle reverted (r2 regression)
    const int t0  = c * LC;

    float S = 0.0f, M = 1.0f;
    float r0,r1,r2,r3,r4,r5,r6,r7;
    float p0,p1,p2,p3,p4,p5,p6,p7;
    float w0,w1,w2,w3,w4,w5,w6,w7;

    const float2* __restrict__ prob2  = (const float2*)prob;
    const float2* __restrict__ aprob2 = (const float2*)aprob;
    const size_t base = (size_t)t0 * B_DIM + b;

    // ---- load cluster: all 8 timesteps' inputs issued back-to-back ----
#define LOADA(i)                                                            \
    const size_t idx##i = base + (size_t)(i) * B_DIM;                       \
    const float2 pr##i = prob2[idx##i];                                     \
    const float2 qr##i = aprob2[idx##i];                                    \
    const float  vv##i = v[idx##i];                                         \
    const float  rr##i = rw[idx##i];                                        \
    const int    a##i  = act[idx##i];                                       \
    const int    d##i  = dnn[idx##i];

    LOADA(0) LOADA(1) LOADA(2) LOADA(3) LOADA(4) LOADA(5) LOADA(6) LOADA(7)
#undef LOADA

    // ---- compute: reverse order composes f_t(x) = (vv+p) + m*x ----
#define CALCA(i)                                                            \
    {                                                                       \
        float pa    = a##i ? pr##i.y : pr##i.x;                             \
        float qa    = a##i ? qr##i.y : qr##i.x;                             \
        float ratio = (pa * (qr##i.x + qr##i.y)) /                          \
                      ((pr##i.x + pr##i.y) * qa);                           \
        float rho   = fminf(ratio, 1.0f);                                   \
        float m     = d##i ? 0.0f : GAMMA * rho;                            \
        float p     = rho * (rr##i - vv##i);                                \
        r##i = __uint_as_float(__float_as_uint(ratio) |                     \
                               ((unsigned)d##i << 31));                     \
        p##i = p;                                                           \
        w##i = vv##i;                                                       \
        S = (vv##i + p) + m * S;                                            \
        M = m * M;                                                          \
    }

    CALCA(7) CALCA(6) CALCA(5) CALCA(4) CALCA(3) CALCA(2) CALCA(1) CALCA(0)
#undef CALCA

    Sc[c][bl] = S;
    Mc[c][bl] = M;
    __syncthreads();

    // serial cross-chunk scan (reverse over time), one thread per column
    if (tid < GB) {
        float carry = nv[(size_t)(T_DIM - 1) * B_DIM + blockIdx.x * GB + tid];
#pragma unroll 8
        for (int cc = NC - 1; cc >= 0; --cc) {
            Cin[cc][tid] = carry;                  // carry entering chunk cc
            carry = fmaf(Mc[cc][tid], carry, Sc[cc][tid]);
        }
    }
    __syncthreads();

    float carry  = Cin[c][bl];
    float critic = 0.0f, msum = 0.0f;

#define STEPB(i)                                                            \
    {                                                                       \
        const unsigned u  = __float_as_uint(r##i);                          \
        const float r_    = __uint_as_float(u & 0x7fffffffu);               \
        const float m     = ((int)u < 0) ? 0.0f : GAMMA * fminf(r_, 1.0f);  \
        const float adv   = fmaf(m, carry, p##i);                           \
        carry = w##i + adv;                                                 \
        critic = fmaf(adv, adv, critic);                                    \
        msum += (adv >= 0.0f) ? fminf(r_, 1.2f) * adv                       \
                              : fmaxf(r_, 0.8f) * adv;                      \
    }

    STEPB(7) STEPB(6) STEPB(5) STEPB(4) STEPB(3) STEPB(2) STEPB(1) STEPB(0)
#undef STEPB

    // block reduction: wave64 shuffle then cross-wave via LDS (16 waves)
#pragma unroll
    for (int off = 32; off > 0; off >>= 1) {
        critic += __shfl_down(critic, off, 64);
        msum   += __shfl_down(msum, off, 64);
    }
    const int wave = tid >> 6;
    if ((tid & 63) == 0) { red[wave] = critic; red[16 + wave] = msum; }
    __syncthreads();
    if (tid == 0) {
        float cs = 0.0f, ms = 0.0f;
#pragma unroll
        for (int w = 0; w < 16; ++w) { cs += red[w]; ms += red[16 + w]; }
        partials[blockIdx.x]       = cs;   // critic partial (SoA for finalize)
        partials[512 + blockIdx.x] = ms;   // min-surrogate partial
    }
}

__global__ void vtrace_final(const float* __restrict__ partials,
                             float* __restrict__ out) {
    __shared__ float red[16];
    const int tid = threadIdx.x;  // 512 threads, one per main-block partial
    float cs = partials[tid];
    float ms = partials[512 + tid];
#pragma unroll
    for (int off = 32; off > 0; off >>= 1) {
        cs += __shfl_down(cs, off, 64);
        ms += __shfl_down(ms, off, 64);
    }
    const int wave = tid >> 6;
    if ((tid & 63) == 0) { red[wave] = cs; red[8 + wave] = ms; }
    __syncthreads();
    if (tid == 0) {
        float c = 0.0f, m = 0.0f;
#pragma unroll
        for (int w = 0; w < 8; ++w) { c += red[w]; m += red[8 + w]; }
        const float invN = 1.0f / (float)((size_t)T_DIM * B_DIM); // exact pow2
        // total = actor + critic = -mean(min(surr)) + 0.5*mean(adv^2)
        out[0] = 0.5f * c * invN - m * invN;
    }
}

extern "C" void kernel_launch(void* const* d_in, const int* in_sizes, int n_in,
                              void* d_out, int out_size, void* d_ws, size_t ws_size,
                              hipStream_t stream) {
    const float* prob  = (const float*)d_in[0];
    const float* aprob = (const float*)d_in[1];
    const float* v     = (const float*)d_in[2];
    const float* nv    = (const float*)d_in[3];
    const float* rw    = (const float*)d_in[4];
    const int*   act   = (const int*)d_in[5];
    const int*   dnn   = (const int*)d_in[6];
    float* partials = (float*)d_ws;   // 1024 floats used
    float* out      = (float*)d_out;

    vtrace_main<<<B_DIM / GB, GB * NC, 0, stream>>>(prob, aprob, v, nv, rw,
                                                    act, dnn, partials);
    vtrace_final<<<1, 512, 0, stream>>>(partials, out);
}

// Round 4
// 168.884 us; speedup vs baseline: 1.0491x; 1.0031x over previous
//
#include <hip/hip_runtime.h>

#define T_DIM 512
#define B_DIM 8192
#define GB 16      // batch columns per block
#define NC 64      // time chunks
#define LC 8       // timesteps per chunk  (NC*LC == T_DIM)
#define NTH (GB * NC)   // 1024 threads
#define GAMMA 0.99f

// Rounds 0-3 post-mortem: the backend register allocator pins VGPR=32 and
// spills ~16 floats/thread of cross-phase state to scratch -> 35 MB of
// HBM write traffic + full-latency reloads inside phase B, regardless of
// __launch_bounds__. Fix is structural, not persuasive:
//   (a) ALL cross-phase per-thread state (r,p,s per timestep) lives in LDS
//       slabs st_*[LC][NTH] — same-thread producer/consumer, no barrier,
//       bank = tid%32 -> 2 lanes/bank = conflict-free. Spill impossible.
//   (b) amdgpu_waves_per_eu(4,4) pins occupancy target = 4 waves/EU
//       (the LDS cap anyway: 108 KB -> 1 block/CU) so the allocator gets
//       an honest 128-VGPR budget for the phase-A load cluster (MLP).
__global__ __launch_bounds__(1024)
__attribute__((amdgpu_waves_per_eu(4, 4)))
void vtrace_main(const float* __restrict__ prob,
                 const float* __restrict__ aprob,
                 const float* __restrict__ v,
                 const float* __restrict__ nv,
                 const float* __restrict__ rw,
                 const int* __restrict__ act,
                 const int* __restrict__ dnn,
                 float* __restrict__ partials) {
    __shared__ float st_r[LC][NTH];   // ratio, done bit in sign   (32 KB)
    __shared__ float st_p[LC][NTH];   // p = rho*(rr - vv)         (32 KB)
    __shared__ float st_s[LC][NTH];   // s = vv + p                (32 KB)
    __shared__ float Sc[NC][GB];
    __shared__ float Mc[NC][GB];
    __shared__ float Cin[NC][GB];
    __shared__ float red[32];

    const int tid = threadIdx.x;
    const int bl  = tid & (GB - 1);
    const int c   = tid >> 4;
    const int b   = blockIdx.x * GB + bl;
    const int t0  = c * LC;

    const float2* __restrict__ prob2  = (const float2*)prob;
    const float2* __restrict__ aprob2 = (const float2*)aprob;
    const size_t base = (size_t)t0 * B_DIM + b;

    // ---- load cluster: all 8 timesteps' inputs issued back-to-back ----
#define LOADA(i)                                                            \
    const size_t idx##i = base + (size_t)(i) * B_DIM;                       \
    const float2 pr##i = prob2[idx##i];                                     \
    const float2 qr##i = aprob2[idx##i];                                    \
    const float  vv##i = v[idx##i];                                         \
    const float  rr##i = rw[idx##i];                                        \
    const int    a##i  = act[idx##i];                                       \
    const int    d##i  = dnn[idx##i];

    LOADA(0) LOADA(1) LOADA(2) LOADA(3) LOADA(4) LOADA(5) LOADA(6) LOADA(7)
#undef LOADA

    // ---- compute & stash to LDS; reverse order composes f_t = s + m*x ----
    float S = 0.0f, M = 1.0f;
#define CALCA(i)                                                            \
    {                                                                       \
        float pa    = a##i ? pr##i.y : pr##i.x;                             \
        float qa    = a##i ? qr##i.y : qr##i.x;                             \
        float ratio = (pa * (qr##i.x + qr##i.y)) /                          \
                      ((pr##i.x + pr##i.y) * qa);                           \
        float rho   = fminf(ratio, 1.0f);                                   \
        float m     = d##i ? 0.0f : GAMMA * rho;                            \
        float p     = rho * (rr##i - vv##i);                                \
        st_r[i][tid] = __uint_as_float(__float_as_uint(ratio) |             \
                                       ((unsigned)d##i << 31));             \
        st_p[i][tid] = p;                                                   \
        st_s[i][tid] = vv##i + p;                                           \
        S = (vv##i + p) + m * S;                                            \
        M = m * M;                                                          \
    }

    CALCA(7) CALCA(6) CALCA(5) CALCA(4) CALCA(3) CALCA(2) CALCA(1) CALCA(0)
#undef CALCA

    Sc[c][bl] = S;
    Mc[c][bl] = M;
    __syncthreads();

    // serial cross-chunk scan (reverse over time), one lane per column
    if (tid < GB) {
        float carry = nv[(size_t)(T_DIM - 1) * B_DIM + blockIdx.x * GB + tid];
#pragma unroll 8
        for (int cc = NC - 1; cc >= 0; --cc) {
            Cin[cc][tid] = carry;                  // carry entering chunk cc
            carry = fmaf(Mc[cc][tid], carry, Sc[cc][tid]);
        }
    }
    __syncthreads();

    // ---- phase B: replay chunk from LDS with corrected carry ----
    float carry  = Cin[c][bl];
    float critic = 0.0f, msum = 0.0f;

#define STEPB(i)                                                            \
    {                                                                       \
        const unsigned u  = __float_as_uint(st_r[i][tid]);                  \
        const float r_    = __uint_as_float(u & 0x7fffffffu);               \
        const float m     = ((int)u < 0) ? 0.0f : GAMMA * fminf(r_, 1.0f);  \
        const float t_    = m * carry;                                      \
        const float adv   = st_p[i][tid] + t_;    /* == -(v - vtrace) */    \
        carry = st_s[i][tid] + t_;                /* vtrace_t */            \
        critic = fmaf(adv, adv, critic);                                    \
        msum += (adv >= 0.0f) ? fminf(r_, 1.2f) * adv                       \
                              : fmaxf(r_, 0.8f) * adv;                      \
    }

    STEPB(7) STEPB(6) STEPB(5) STEPB(4) STEPB(3) STEPB(2) STEPB(1) STEPB(0)
#undef STEPB

    // block reduction: wave64 shuffle then cross-wave via LDS (16 waves)
#pragma unroll
    for (int off = 32; off > 0; off >>= 1) {
        critic += __shfl_down(critic, off, 64);
        msum   += __shfl_down(msum, off, 64);
    }
    const int wave = tid >> 6;
    if ((tid & 63) == 0) { red[wave] = critic; red[16 + wave] = msum; }
    __syncthreads();
    if (tid == 0) {
        float cs = 0.0f, ms = 0.0f;
#pragma unroll
        for (int w = 0; w < 16; ++w) { cs += red[w]; ms += red[16 + w]; }
        partials[blockIdx.x]       = cs;   // critic partial (SoA for finalize)
        partials[512 + blockIdx.x] = ms;   // min-surrogate partial
    }
}

__global__ void vtrace_final(const float* __restrict__ partials,
                             float* __restrict__ out) {
    __shared__ float red[16];
    const int tid = threadIdx.x;  // 512 threads, one per main-block partial
    float cs = partials[tid];
    float ms = partials[512 + tid];
#pragma unroll
    for (int off = 32; off > 0; off >>= 1) {
        cs += __shfl_down(cs, off, 64);
        ms += __shfl_down(ms, off, 64);
    }
    const int wave = tid >> 6;
    if ((tid & 63) == 0) { red[wave] = cs; red[8 + wave] = ms; }
    __syncthreads();
    if (tid == 0) {
        float c = 0.0f, m = 0.0f;
#pragma unroll
        for (int w = 0; w < 8; ++w) { c += red[w]; m += red[8 + w]; }
        const float invN = 1.0f / (float)((size_t)T_DIM * B_DIM); // exact pow2
        // total = actor + critic = -mean(min(surr)) + 0.5*mean(adv^2)
        out[0] = 0.5f * c * invN - m * invN;
    }
}

extern "C" void kernel_launch(void* const* d_in, const int* in_sizes, int n_in,
                              void* d_out, int out_size, void* d_ws, size_t ws_size,
                              hipStream_t stream) {
    const float* prob  = (const float*)d_in[0];
    const float* aprob = (const float*)d_in[1];
    const float* v     = (const float*)d_in[2];
    const float* nv    = (const float*)d_in[3];
    const float* rw    = (const float*)d_in[4];
    const int*   act   = (const int*)d_in[5];
    const int*   dnn   = (const int*)d_in[6];
    float* partials = (float*)d_ws;   // 1024 floats used
    float* out      = (float*)d_out;

    vtrace_main<<<B_DIM / GB, NTH, 0, stream>>>(prob, aprob, v, nv, rw,
                                                act, dnn, partials);
    vtrace_final<<<1, 512, 0, stream>>>(partials, out);
}